// Round 1
// baseline (23.572 us; speedup 1.0000x reference)
//
#include <hip/hip_runtime.h>

#define B_TOTAL 2048
#define T_LEN 128
#define C_DIM 8
#define NOUT 10
#define SIG_DIM 584          // 8 + 64 + 512
#define WAVES_PER_BLOCK 4

// One wave per batch element. Lane l = (i,j), i=l>>3, j=l&7.
// Lane state: S3[i][j][0..7] (8 regs), S2[i][j] (1 reg), S1[i], S1[j] (2 regs).
// Chen step with increment dx:
//   S3[i][j][k] += (dx_i*dx_j/6 + S1_i*dx_j/2 + S2_ij) * dx_k
//   S2[i][j]    += dx_i*dx_j/2 + S1_i*dx_j
//   S1[i]       += dx_i
__global__ __launch_bounds__(256) void sig_linear_kernel(
    const float* __restrict__ X, const float* __restrict__ W,
    const float* __restrict__ bias, float* __restrict__ out)
{
    __shared__ __align__(16) float lds[WAVES_PER_BLOCK][T_LEN * C_DIM];
    const int tid = threadIdx.x;
    const int w = tid >> 6;
    const int l = tid & 63;
    const int b = blockIdx.x * WAVES_PER_BLOCK + w;
    const int i = l >> 3;
    const int j = l & 7;

    // Stage this batch's path (128 rows x 8 floats = 4 KB) into LDS, coalesced.
    const float4* Xb4 = reinterpret_cast<const float4*>(X + (size_t)b * (T_LEN * C_DIM));
    float4* lds4 = reinterpret_cast<float4*>(&lds[w][0]);
#pragma unroll
    for (int r = 0; r < 4; ++r) lds4[r * 64 + l] = Xb4[r * 64 + l];
    __syncthreads();

    const float* L = &lds[w][0];

    float s3[8];
#pragma unroll
    for (int k = 0; k < 8; ++k) s3[k] = 0.f;
    float s2 = 0.f, s1i = 0.f, s1j = 0.f;

    // previous row (wave-uniform) + per-lane previous x_i, x_j
    float xp[8];
    {
        float4 r0 = *reinterpret_cast<const float4*>(L);
        float4 r1 = *reinterpret_cast<const float4*>(L + 4);
        xp[0] = r0.x; xp[1] = r0.y; xp[2] = r0.z; xp[3] = r0.w;
        xp[4] = r1.x; xp[5] = r1.y; xp[6] = r1.z; xp[7] = r1.w;
    }
    float xpi = L[i], xpj = L[j];

    for (int t = 1; t < T_LEN; ++t) {
        const float* row = L + t * C_DIM;
        float4 r0 = *reinterpret_cast<const float4*>(row);
        float4 r1 = *reinterpret_cast<const float4*>(row + 4);
        float xc[8];
        xc[0] = r0.x; xc[1] = r0.y; xc[2] = r0.z; xc[3] = r0.w;
        xc[4] = r1.x; xc[5] = r1.y; xc[6] = r1.z; xc[7] = r1.w;
        float xci = row[i], xcj = row[j];

        float dx[8];
#pragma unroll
        for (int k = 0; k < 8; ++k) { dx[k] = xc[k] - xp[k]; xp[k] = xc[k]; }
        float dxi = xci - xpi, dxj = xcj - xpj;
        xpi = xci; xpj = xcj;

        float cij = dxi * dxj;
        // f uses OLD s2, s1i (Chen: cross terms use previous-level state)
        float f = s2 + 0.5f * s1i * dxj + (1.0f / 6.0f) * cij;
#pragma unroll
        for (int k = 0; k < 8; ++k) s3[k] = fmaf(f, dx[k], s3[k]);
        s2 = fmaf(0.5f, cij, fmaf(s1i, dxj, s2));
        s1i += dxi;
        s1j += dxj;
    }

    // Epilogue: out[b][o] = bias[o] + W[o][:] . sig[b][:]
    // sig layout: [0..7]=S1, [8+l]=S2[i][j] (l=i*8+j), [72 + l*8 + k]=S3[i][j][k]
#pragma unroll
    for (int o = 0; o < NOUT; ++o) {
        const float* wrow = W + o * SIG_DIM;
        float part = s2 * wrow[8 + l];
        const float4 w0 = *reinterpret_cast<const float4*>(wrow + 72 + l * 8);
        const float4 w1 = *reinterpret_cast<const float4*>(wrow + 72 + l * 8 + 4);
        part = fmaf(s3[0], w0.x, part); part = fmaf(s3[1], w0.y, part);
        part = fmaf(s3[2], w0.z, part); part = fmaf(s3[3], w0.w, part);
        part = fmaf(s3[4], w1.x, part); part = fmaf(s3[5], w1.y, part);
        part = fmaf(s3[6], w1.z, part); part = fmaf(s3[7], w1.w, part);
        if (i == 0) part = fmaf(s1j, wrow[j], part);  // lanes 0..7 hold S1[j=l]
#pragma unroll
        for (int off = 32; off > 0; off >>= 1) part += __shfl_xor(part, off);
        if (l == 0) out[b * NOUT + o] = part + bias[o];
    }
}

extern "C" void kernel_launch(void* const* d_in, const int* in_sizes, int n_in,
                              void* d_out, int out_size, void* d_ws, size_t ws_size,
                              hipStream_t stream) {
    const float* X = (const float*)d_in[0];     // (2048, 128, 8)
    const float* W = (const float*)d_in[1];     // (10, 584)
    const float* bias = (const float*)d_in[2];  // (10,)
    float* out = (float*)d_out;                 // (2048, 10)
    dim3 grid(B_TOTAL / WAVES_PER_BLOCK);
    dim3 block(64 * WAVES_PER_BLOCK);
    sig_linear_kernel<<<grid, block, 0, stream>>>(X, W, bias, out);
}